// Round 4
// baseline (373.577 us; speedup 1.0000x reference)
//
#include <hip/hip_runtime.h>
#include <cmath>

#define NN 512

__device__ __forceinline__ int is_inf_f(float x) {
    return (__float_as_uint(x) & 0x7fffffffu) == 0x7f800000u;
}

// quad_perm DPP broadcast-free lane exchange (VALU pipe, not DS)
template<int CTRL>
__device__ __forceinline__ float fdpp(float v) {
    return __int_as_float(__builtin_amdgcn_mov_dpp(__float_as_int(v), CTRL, 0xf, 0xf, false));
}
#define DPP_XOR1 0xB1   // quad_perm [1,0,3,2]
#define DPP_XOR2 0x4E   // quad_perm [2,3,0,1]

// e = ef[1:4] = sqrt(3) * u[[1,2,0]] with the reference's exact epsilon fudges
__device__ __forceinline__ void edge_vec(float ci0, float ci1, float ci2,
                                         float cj0, float cj1, float cj2,
                                         float& e0, float& e1, float& e2) {
    float d0 = ci0 - cj0, d1 = ci1 - cj1, d2 = ci2 - cj2;
    float den = sqrtf(d0*d0 + d1*d1 + d2*d2 + 1e-12f) + 1e-5f;
    float r = 1.0f / den;
    d0 *= r; d1 *= r; d2 *= r;
    float n = sqrtf(d0*d0 + d1*d1 + d2*d2 + 1e-12f);
    float s = 1.7320508075688772f / n;
    e0 = d1 * s;  // sqrt3*u_y
    e1 = d2 * s;  // sqrt3*u_z
    e2 = d0 * s;  // sqrt3*u_x
}

// K1: block = (b, i-quad). Transpose attn_disp -> ad (inf->0, required output,
// i-major) AND adT (j-major, scribbled into the mask_out region — dead until
// k_final rewrites it). Also edge features + normalizer.  (unchanged, verified)
__global__ __launch_bounds__(256) void k_trans(
    const float* __restrict__ disp, const float* __restrict__ coords,
    float* __restrict__ ad_out, float* __restrict__ adT_out,
    float* __restrict__ ef_out, float* __restrict__ ws_norm)
{
    __shared__ float L[256 * 20];          // 20 KiB, pad-20 => conflict-free
    const int blk = blockIdx.x;            // 512 = 4 b * 128 i-quads
    const int b   = blk >> 7;
    const int i0  = (blk & 127) << 2;
    const int tid = threadIdx.x;
    const int il  = tid >> 6;              // wave id == local i (0..3)
    const int jl  = tid & 63;
    const int i   = i0 + il;
    const float ci0 = coords[(b*NN+i)*3+0];
    const float ci1 = coords[(b*NN+i)*3+1];
    const float ci2 = coords[(b*NN+i)*3+2];
    int cnt = 0;
    for (int ch = 0; ch < 8; ch++) {       // j-chunks of 64
        const int j = ch*64 + jl;
        float v[16];
        #pragma unroll
        for (int h = 0; h < 16; h++) {
            float x = disp[(size_t)((b*16+h)*NN + i)*NN + j];   // 256B coalesced
            int bad = is_inf_f(x);
            if (h == 0) cnt += 1 - bad;
            v[h] = bad ? 0.0f : x;
        }
        float4* dst = (float4*)(ad_out + (size_t)((b*NN+i)*NN + j)*16);
        dst[0] = make_float4(v[0], v[1], v[2], v[3]);
        dst[1] = make_float4(v[4], v[5], v[6], v[7]);
        dst[2] = make_float4(v[8], v[9], v[10], v[11]);
        dst[3] = make_float4(v[12], v[13], v[14], v[15]);
        {
            const float cj0 = coords[(b*NN+j)*3+0];
            const float cj1 = coords[(b*NN+j)*3+1];
            const float cj2 = coords[(b*NN+j)*3+2];
            float e0, e1, e2;
            edge_vec(ci0, ci1, ci2, cj0, cj1, cj2, e0, e1, e2);
            ((float4*)ef_out)[(size_t)(b*NN+i)*NN + j] = make_float4(1.0f, e0, e1, e2);
        }
        {
            float4* Lr = (float4*)(L + tid*20);
            Lr[0] = make_float4(v[0], v[1], v[2], v[3]);
            Lr[1] = make_float4(v[4], v[5], v[6], v[7]);
            Lr[2] = make_float4(v[8], v[9], v[10], v[11]);
            Lr[3] = make_float4(v[12], v[13], v[14], v[15]);
        }
        __syncthreads();
        #pragma unroll
        for (int p = 0; p < 4; p++) {
            const int jj  = (tid >> 4) + p*16;   // 0..63
            const int f   = tid & 15;
            const int iw  = f >> 2, w4 = f & 3;
            const int row = iw*64 + jj;
            float4 val = *(const float4*)(L + row*20 + w4*4);
            ((float4*)adT_out)[(size_t)((b*NN + ch*64 + jj)*NN + (i0 + iw))*4 + w4] = val;
        }
        __syncthreads();
    }
    #pragma unroll
    for (int off = 32; off >= 1; off >>= 1) cnt += __shfl_xor(cnt, off);
    if (jl == 0) ws_norm[b*NN + i] = sqrtf((float)cnt);
}

// K2 v5: block = (b,j). Lane decomposition l = (g:2 | qg:2 | q:2):
//   q  = l&3       : h-quarter owned (and DPP xor-perm slot)
//   qg = (l>>2)&3  : quad-group -> col offset 4*qg
//   g  = l>>4      : which of 4 i's this lane loads per batch
// One dwordx4 wave-instr covers FOUR A[i] lines (256B useful, 4x fewer VMEM
// instrs than v4); one ds_read_b128 covers 4 E entries. Cols covered by 4
// register-resident rounds r (cols 16r+4qg+(x^q), weights preloaded: 64 VGPR).
// Quad DPP tree (verified r3): t_q = full dot of col (16r+4qg+q). After the
// i-loop, shfl_xor(16/32) sums the 4 g-groups; lanes 0..15 write R4 in the
// same [wv*64+col] format as v3/v4 — downstream combine unchanged.
__global__ __launch_bounds__(256) void k_reduce5(
    const float* __restrict__ adT, const float* __restrict__ coords,
    const float* __restrict__ wA, const float* __restrict__ wB,  // fc1_w1, fc2_w1 (16x32)
    float* __restrict__ ws)
{
    __shared__ float4 E4[NN];        // {e0,e1,e2,0} per i   (8 KiB)
    __shared__ float4 R4[4*64];      // per-wave partial acc  (4 KiB)
    __shared__ float  sred[12];
    const int blk  = blockIdx.x;     // 2048 = B*N
    const int b    = blk >> 9, j = blk & 511;
    const int tid  = threadIdx.x;
    const int lane = tid & 63;
    const int wv   = tid >> 6;       // 0..3
    const int q    = lane & 3;
    const int qg   = (lane >> 2) & 3;
    const int g    = lane >> 4;
    const float cj0 = coords[(b*NN+j)*3+0];
    const float cj1 = coords[(b*NN+j)*3+1];
    const float cj2 = coords[(b*NN+j)*3+2];
    // ---- fill E table (2 i's per thread) + Se partials ----
    float se0 = 0.f, se1 = 0.f, se2 = 0.f;
    #pragma unroll
    for (int r = 0; r < 2; r++) {
        const int i = r*256 + tid;
        const float ci0 = coords[(b*NN+i)*3+0];
        const float ci1 = coords[(b*NN+i)*3+1];
        const float ci2 = coords[(b*NN+i)*3+2];
        float e0, e1, e2;
        edge_vec(ci0, ci1, ci2, cj0, cj1, cj2, e0, e1, e2);
        E4[i] = make_float4(e0, e1, e2, 0.f);
        se0 += e0; se1 += e1; se2 += e2;
    }
    // ---- per-lane weights: rounds r=0..3 (r<2: net A, r>=2: net B),
    //      cols 16*(r&1)+4*qg+(x^q), my h-quarter rows 4q..4q+3 ----
    float wr[4][4][4];               // [r][x][hh]
    #pragma unroll
    for (int r = 0; r < 4; r++) {
        const float* __restrict__ Wn = (r < 2) ? wA : wB;
        const int base = 16*(r & 1) + 4*qg;
        #pragma unroll
        for (int x = 0; x < 4; x++) {
            const int c = base + (x ^ q);
            #pragma unroll
            for (int hh = 0; hh < 4; hh++)
                wr[r][x][hh] = Wn[(4*q + hh)*32 + c];
        }
    }
    __syncthreads();
    // ---- stream this wave's i-range: 32 batches of 4 i (1 load + 1 E-read) ----
    const float* __restrict__ Arow = adT + (size_t)((b*NN + j) * NN) * 16;
    float acc[4][4];
    #pragma unroll
    for (int r = 0; r < 4; r++)
        #pragma unroll
        for (int w = 0; w < 4; w++) acc[r][w] = 0.f;
    const int ibase = wv * 128;
    #pragma unroll 4
    for (int kk = 0; kk < 32; kk++) {
        const int i = ibase + 4*kk + g;
        const float4 a = *(const float4*)(Arow + (size_t)i * 16 + q*4);
        const float4 ev = E4[i];
        #pragma unroll
        for (int r = 0; r < 4; r++) {
            float P0, P1, P2, P3;
            P0 = a.x * wr[r][0][0];
            P0 = fmaf(a.y, wr[r][0][1], P0);
            P0 = fmaf(a.z, wr[r][0][2], P0);
            P0 = fmaf(a.w, wr[r][0][3], P0);
            P1 = a.x * wr[r][1][0];
            P1 = fmaf(a.y, wr[r][1][1], P1);
            P1 = fmaf(a.z, wr[r][1][2], P1);
            P1 = fmaf(a.w, wr[r][1][3], P1);
            P2 = a.x * wr[r][2][0];
            P2 = fmaf(a.y, wr[r][2][1], P2);
            P2 = fmaf(a.z, wr[r][2][2], P2);
            P2 = fmaf(a.w, wr[r][2][3], P2);
            P3 = a.x * wr[r][3][0];
            P3 = fmaf(a.y, wr[r][3][1], P3);
            P3 = fmaf(a.z, wr[r][3][2], P3);
            P3 = fmaf(a.w, wr[r][3][3], P3);
            const float n0 = P0 + fdpp<DPP_XOR1>(P1);
            const float n2 = P2 + fdpp<DPP_XOR1>(P3);
            const float t  = n0 + fdpp<DPP_XOR2>(n2);   // col = 16r+4qg+q
            const float m  = fmaxf(t, 0.f);             // scale folded out
            acc[r][0] += m;
            acc[r][1] = fmaf(ev.x, m, acc[r][1]);
            acc[r][2] = fmaf(ev.y, m, acc[r][2]);
            acc[r][3] = fmaf(ev.z, m, acc[r][3]);
        }
    }
    // sum the 4 g-groups (same col set per 16-lane group)
    #pragma unroll
    for (int r = 0; r < 4; r++)
        #pragma unroll
        for (int w = 0; w < 4; w++) {
            float v = acc[r][w];
            v += __shfl_xor(v, 16);
            v += __shfl_xor(v, 32);
            acc[r][w] = v;
        }
    if (lane < 16) {
        #pragma unroll
        for (int r = 0; r < 4; r++)
            R4[wv*64 + 16*r + lane] = make_float4(acc[r][0], acc[r][1], acc[r][2], acc[r][3]);
    }
    // Se: butterfly within wave, cross-wave via LDS
    #pragma unroll
    for (int off = 1; off < 64; off <<= 1) {
        se0 += __shfl_xor(se0, off);
        se1 += __shfl_xor(se1, off);
        se2 += __shfl_xor(se2, off);
    }
    if (lane == 0) { sred[wv*3+0] = se0; sred[wv*3+1] = se1; sred[wv*3+2] = se2; }
    __syncthreads();
    // ---- combine 4 waves, apply relu scale, store accg ----
    {
        const int col = tid & 63, wq2 = tid >> 6;   // 256 threads = 64 cols x 4 w
        const float* Rf = (const float*)R4;
        float v = Rf[(0*64+col)*4 + wq2] + Rf[(1*64+col)*4 + wq2]
                + Rf[(2*64+col)*4 + wq2] + Rf[(3*64+col)*4 + wq2];
        v *= 0.35355339059327373f;                 // 0.25 * sqrt(2)
        float* accg = ws + 2048*4 + (size_t)blk*256;
        accg[((col >> 5)*4 + wq2)*32 + (col & 31)] = v;
    }
    if (tid == 0) {
        float* seg = ws + 2048 + blk*3;
        seg[0] = sred[0]+sred[3]+sred[6]+sred[9];
        seg[1] = sred[1]+sred[4]+sred[7]+sred[10];
        seg[2] = sred[2]+sred[5]+sred[8]+sred[11];
    }
}

// K3: blocks 0..7 = per-node W2 + Wigner/gate algebra (unchanged, verified);
// blocks 8..519 = mask passthrough (adT region is dead now) + coords copy.
__global__ __launch_bounds__(256) void k_final(
    const float* __restrict__ ws,
    const float* __restrict__ w2a,   // fc1_w2 (32x14)
    const float* __restrict__ w2b,   // fc2_w2 (32x12)
    float* __restrict__ nf_out,
    const float* __restrict__ mask, float* __restrict__ mask_out,
    const float* __restrict__ coords, float* __restrict__ coords_out)
{
    if (blockIdx.x >= 8) {
        const int cblk = blockIdx.x - 8;              // 0..511
        const float4* mi = (const float4*)mask;
        float4* mo = (float4*)mask_out;
        const size_t base = (size_t)cblk * 8192;
        #pragma unroll
        for (int r = 0; r < 32; r++) mo[base + r*256 + threadIdx.x] = mi[base + r*256 + threadIdx.x];
        if (cblk == 0) {
            for (int idx = threadIdx.x; idx < 4*NN*3; idx += 256) coords_out[idx] = coords[idx];
        }
        return;
    }
    const int bj = blockIdx.x*256 + threadIdx.x;   // 2048
    const float inv = 1.0f / ws[bj];
    const float s  = 512.0f * inv;                 // nf0 scalar = N/norm
    const float vv0 = ws[2048 + bj*3 + 0] * inv;
    const float vv1 = ws[2048 + bj*3 + 1] * inv;
    const float vv2 = ws[2048 + bj*3 + 2] * inv;
    const float* acc = ws + 2048*4 + (size_t)bj*256;
    const float ksc = 0.17677669529663687f;        // 1/sqrt(32) (fc second layer)
    float S0[14], S1[3][14];
    #pragma unroll
    for (int cc = 0; cc < 14; cc++) { S0[cc]=0.f; S1[0][cc]=0.f; S1[1][cc]=0.f; S1[2][cc]=0.f; }
    for (int c = 0; c < 32; c++) {
        const float p = acc[c], q0 = acc[32+c], q1 = acc[64+c], q2 = acc[96+c];
        #pragma unroll
        for (int cc = 0; cc < 14; cc++) {
            const float w = w2a[c*14+cc];
            S0[cc]    = fmaf(p,  w, S0[cc]);
            S1[0][cc] = fmaf(q0, w, S1[0][cc]);
            S1[1][cc] = fmaf(q1, w, S1[1][cc]);
            S1[2][cc] = fmaf(q2, w, S1[2][cc]);
        }
    }
    #pragma unroll
    for (int cc = 0; cc < 14; cc++) { S0[cc]*=ksc; S1[0][cc]*=ksc; S1[1][cc]*=ksc; S1[2][cc]*=ksc; }
    const float is2 = 0.7071067811865476f;   // 1/sqrt2
    const float is3 = 0.5773502691896258f;   // 1/sqrt3
    float x0[4];
    #pragma unroll
    for (int k = 0; k < 4; k++)
        x0[k] = inv*is2*( s*S0[k] + is3*(vv0*S1[0][4+k] + vv1*S1[1][4+k] + vv2*S1[2][4+k]) );
    const float vv[3] = {vv0, vv1, vv2};
    float x8[3];
    #pragma unroll
    for (int k = 0; k < 3; k++)
        x8[k] = inv*is2*( s*S1[k][8] + vv[k]*S0[10] );
    const float E12_0=S1[0][12], E12_1=S1[1][12], E12_2=S1[2][12];
    float x14[3];
    x14[0] = inv*is2*(vv1*E12_2 - vv2*E12_1);
    x14[1] = inv*is2*(vv2*E12_0 - vv0*E12_2);
    x14[2] = inv*is2*(vv0*E12_1 - vv1*E12_0);
    const float a0 = fmaxf(x0[0],0.f), a1 = fmaxf(x0[1],0.f);
    const float g1 = fmaxf(x0[2],0.f), g3 = fmaxf(x0[3],0.f);
    const float p0=x8[0]*g1,  p1=x8[1]*g1,  p2=x8[2]*g1;
    const float q0_=x14[0]*g3, q1_=x14[1]*g3, q2_=x14[2]*g3;
    float T0[12], T1[3][12];
    #pragma unroll
    for (int cc = 0; cc < 12; cc++){ T0[cc]=0.f; T1[0][cc]=0.f; T1[1][cc]=0.f; T1[2][cc]=0.f; }
    const float* acc2 = acc + 128;
    for (int c = 0; c < 32; c++) {
        const float p = acc2[c], r0 = acc2[32+c], r1 = acc2[64+c], r2 = acc2[96+c];
        #pragma unroll
        for (int cc = 0; cc < 12; cc++) {
            const float w = w2b[c*12+cc];
            T0[cc]    = fmaf(p,  w, T0[cc]);
            T1[0][cc] = fmaf(r0, w, T1[0][cc]);
            T1[1][cc] = fmaf(r1, w, T1[1][cc]);
            T1[2][cc] = fmaf(r2, w, T1[2][cc]);
        }
    }
    #pragma unroll
    for (int cc = 0; cc < 12; cc++){ T0[cc]*=ksc; T1[0][cc]*=ksc; T1[1][cc]*=ksc; T1[2][cc]*=ksc; }
    const float is6  = 0.4082482904638631f;    // 1/sqrt6
    const float is12 = 0.28867513459481287f;   // 1/sqrt12
    const float E0[3] = {T1[0][0], T1[1][0], T1[2][0]};
    const float E1[3] = {T1[0][1], T1[1][1], T1[2][1]};
    const float E4[3] = {T1[0][4], T1[1][4], T1[2][4]};
    const float E8[3] = {T1[0][8], T1[1][8], T1[2][8]};
    const float cq0 = q1_*E4[2] - q2_*E4[1];
    const float cq1 = q2_*E4[0] - q0_*E4[2];
    const float cq2 = q0_*E4[1] - q1_*E4[0];
    const float cp0 = p1*E8[2] - p2*E8[1];
    const float cp1 = p2*E8[0] - p0*E8[2];
    const float cp2 = p0*E8[1] - p1*E8[0];
    float o[6];
    o[0] = inv*( is6*(a0*E0[0] + a1*E1[0]) + is6*p0*T0[2] + is12*cq0 );
    o[1] = inv*( is6*(a0*E0[1] + a1*E1[1]) + is6*p1*T0[2] + is12*cq1 );
    o[2] = inv*( is6*(a0*E0[2] + a1*E1[2]) + is6*p2*T0[2] + is12*cq2 );
    o[3] = inv*( is12*cp0 + is6*q0_*T0[10] );
    o[4] = inv*( is12*cp1 + is6*q1_*T0[10] );
    o[5] = inv*( is12*cp2 + is6*q2_*T0[10] );
    #pragma unroll
    for (int k = 0; k < 6; k++) nf_out[bj*6+k] = o[k];
}

extern "C" void kernel_launch(void* const* d_in, const int* in_sizes, int n_in,
                              void* d_out, int out_size, void* d_ws, size_t ws_size,
                              hipStream_t stream) {
    const float* disp   = (const float*)d_in[0];   // (4,16,512,512)
    const float* mask   = (const float*)d_in[1];   // (64,512,512)
    const float* coords = (const float*)d_in[2];   // (4,512,3)
    const float* fc1w1  = (const float*)d_in[3];   // (16,32)
    const float* fc1w2  = (const float*)d_in[4];   // (32,14)
    const float* fc2w1  = (const float*)d_in[5];   // (16,32)
    const float* fc2w2  = (const float*)d_in[6];   // (32,12)
    float* out = (float*)d_out;
    float* ad_out     = out;                        // 16,777,216
    float* mask_out   = out + 16777216;             // 16,777,216
    float* coords_out = out + 33554432;             // 6,144
    float* nf_out     = coords_out + 6144;          // 12,288
    float* ef_out     = nf_out + 12288;             // 4,194,304
    float* ws = (float*)d_ws;   // norm[2048] | Se[2048*3] | acc[2048*256]  (~2.03 MiB)

    // adT (b,j,i,h) lives in the mask_out region until k_final overwrites it.
    float* adT = mask_out;

    k_trans  <<<512,  256, 0, stream>>>(disp, coords, ad_out, adT, ef_out, ws);
    k_reduce5<<<2048, 256, 0, stream>>>(adT, coords, fc1w1, fc2w1, ws);
    k_final  <<<520,  256, 0, stream>>>(ws, fc1w2, fc2w2, nf_out,
                                        mask, mask_out, coords, coords_out);
}

// Round 5
// 332.902 us; speedup vs baseline: 1.1222x; 1.1222x over previous
//
#include <hip/hip_runtime.h>
#include <cmath>

#define NN 512

__device__ __forceinline__ int is_inf_f(float x) {
    return (__float_as_uint(x) & 0x7fffffffu) == 0x7f800000u;
}

// quad_perm DPP broadcast-free lane exchange (VALU pipe, not DS)
template<int CTRL>
__device__ __forceinline__ float fdpp(float v) {
    return __int_as_float(__builtin_amdgcn_mov_dpp(__float_as_int(v), CTRL, 0xf, 0xf, false));
}
#define DPP_XOR1 0xB1   // quad_perm [1,0,3,2]
#define DPP_XOR2 0x4E   // quad_perm [2,3,0,1]

// e = ef[1:4] = sqrt(3) * u[[1,2,0]] with the reference's exact epsilon fudges
__device__ __forceinline__ void edge_vec(float ci0, float ci1, float ci2,
                                         float cj0, float cj1, float cj2,
                                         float& e0, float& e1, float& e2) {
    float d0 = ci0 - cj0, d1 = ci1 - cj1, d2 = ci2 - cj2;
    float den = sqrtf(d0*d0 + d1*d1 + d2*d2 + 1e-12f) + 1e-5f;
    float r = 1.0f / den;
    d0 *= r; d1 *= r; d2 *= r;
    float n = sqrtf(d0*d0 + d1*d1 + d2*d2 + 1e-12f);
    float s = 1.7320508075688772f / n;
    e0 = d1 * s;  // sqrt3*u_y
    e1 = d2 * s;  // sqrt3*u_z
    e2 = d0 * s;  // sqrt3*u_x
}

// K1: block = (b, i). Round-0 proven version: transpose attn_disp -> ad
// (inf->0), edge features, normalizer row counts, mask + coords passthrough.
// NO adT, NO LDS, NO barriers.
__global__ __launch_bounds__(256) void k_stage(
    const float* __restrict__ disp, const float* __restrict__ mask,
    const float* __restrict__ coords,
    float* __restrict__ ad_out, float* __restrict__ mask_out,
    float* __restrict__ coords_out, float* __restrict__ ef_out,
    float* __restrict__ ws_norm)
{
    const int blk = blockIdx.x;            // 2048 = B*N
    const int b = blk >> 9, i = blk & 511;
    const int tid = threadIdx.x;
    const float ci0 = coords[(b*NN+i)*3+0];
    const float ci1 = coords[(b*NN+i)*3+1];
    const float ci2 = coords[(b*NN+i)*3+2];
    int cnt = 0;
    #pragma unroll
    for (int r = 0; r < 2; r++) {
        const int j = r*256 + tid;
        float v[16];
        #pragma unroll
        for (int h = 0; h < 16; h++) {
            float x = disp[(size_t)((b*16+h)*NN + i)*NN + j];   // coalesced rows
            int bad = is_inf_f(x);
            if (h == 0) cnt += 1 - bad;
            v[h] = bad ? 0.0f : x;
        }
        float4* dst = (float4*)(ad_out + (size_t)((b*NN+i)*NN + j)*16); // lane owns full 64B line
        dst[0] = make_float4(v[0], v[1], v[2], v[3]);
        dst[1] = make_float4(v[4], v[5], v[6], v[7]);
        dst[2] = make_float4(v[8], v[9], v[10], v[11]);
        dst[3] = make_float4(v[12], v[13], v[14], v[15]);
        const float cj0 = coords[(b*NN+j)*3+0];
        const float cj1 = coords[(b*NN+j)*3+1];
        const float cj2 = coords[(b*NN+j)*3+2];
        float e0, e1, e2;
        edge_vec(ci0, ci1, ci2, cj0, cj1, cj2, e0, e1, e2);
        ((float4*)ef_out)[(size_t)(b*NN+i)*NN + j] = make_float4(1.0f, e0, e1, e2);
    }
    // attn_mask passthrough: same total element count as attn_disp
    {
        const float4* mi = (const float4*)mask;
        float4* mo = (float4*)mask_out;
        const size_t mbase = (size_t)blk * 2048;
        #pragma unroll
        for (int r = 0; r < 8; r++) mo[mbase + r*256 + tid] = mi[mbase + r*256 + tid];
    }
    if (blk == 0) {
        for (int idx = tid; idx < 4*NN*3; idx += 256) coords_out[idx] = coords[idx];
    }
    // normalizer[b,i] = sqrt(#non-inf in attn_disp[b,0,i,:])
    #pragma unroll
    for (int off = 32; off >= 1; off >>= 1) cnt += __shfl_down(cnt, off);
    __shared__ int sredi[4];
    if ((tid & 63) == 0) sredi[tid >> 6] = cnt;
    __syncthreads();
    if (tid == 0) ws_norm[blk] = sqrtf((float)(sredi[0]+sredi[1]+sredi[2]+sredi[3]));
}

// K2: r3's verified k_reduce4 (measured best), reading ad DIRECTLY (i-major).
// Per instruction the quad-split still touches exactly ONE 64B line
// (ad[b][i][j][0:16], 4 unique 16B addrs x 16-lane broadcast) — now at 32 KB
// i-stride instead of contiguous; L3 absorbs the j/j+1 128B-line sharing
// (proven round 0: FETCH == read-once). Everything else byte-identical to r3.
__global__ __launch_bounds__(256) void k_reduceA(
    const float* __restrict__ ad, const float* __restrict__ coords,
    const float* __restrict__ wA, const float* __restrict__ wB,  // fc1_w1, fc2_w1 (16x32)
    float* __restrict__ ws)
{
    __shared__ float4 E4[NN];        // {e0,e1,e2,0} per i   (8 KiB)
    __shared__ float4 R4[4*64];      // per-wave partial acc  (4 KiB)
    __shared__ float  sred[12];
    const int blk  = blockIdx.x;     // 2048 = B*N
    const int b    = blk >> 9, j = blk & 511;
    const int tid  = threadIdx.x;
    const int lane = tid & 63;
    const int wv   = tid >> 6;       // 0..3
    const float cj0 = coords[(b*NN+j)*3+0];
    const float cj1 = coords[(b*NN+j)*3+1];
    const float cj2 = coords[(b*NN+j)*3+2];
    // ---- fill E table (2 i's per thread) + Se partials ----
    float se0 = 0.f, se1 = 0.f, se2 = 0.f;
    #pragma unroll
    for (int r = 0; r < 2; r++) {
        const int i = r*256 + tid;
        const float ci0 = coords[(b*NN+i)*3+0];
        const float ci1 = coords[(b*NN+i)*3+1];
        const float ci2 = coords[(b*NN+i)*3+2];
        float e0, e1, e2;
        edge_vec(ci0, ci1, ci2, cj0, cj1, cj2, e0, e1, e2);
        E4[i] = make_float4(e0, e1, e2, 0.f);
        se0 += e0; se1 += e1; se2 += e2;
    }
    // ---- per-lane weights: 4 cols of my quad, xor-permuted, my h-quarter ----
    const float* __restrict__ Wsel = (lane < 32) ? wA : wB;
    const int q  = lane & 3;         // h-quarter this lane loads
    const int cb = lane & 28 & 31;   // quad base within the 32-col net
    float wq[4][4];                  // wq[x][hh] : col cb+(x^q), h = 4q+hh
    #pragma unroll
    for (int x = 0; x < 4; x++)
        #pragma unroll
        for (int hh = 0; hh < 4; hh++)
            wq[x][hh] = Wsel[(4*q + hh)*32 + (cb | (x ^ q))];
    __syncthreads();
    // ---- stream this wave's i-range (single pass, 1 dwordx4 per i) ----
    const float* __restrict__ Acol = ad + ((size_t)b*NN*NN + j) * 16;  // column j
    float acc0 = 0.f, acc1 = 0.f, acc2 = 0.f, acc3 = 0.f;
    const int ibase = wv * 128;
    #pragma unroll 8
    for (int k = 0; k < 128; k++) {
        const int i = ibase + k;
        const float4 a = ((const float4*)(Acol + (size_t)i * (NN*16)))[q];  // my 16B quarter
        const float4 ev = E4[i];
        float P0, P1, P2, P3;
        P0 = a.x * wq[0][0];
        P0 = fmaf(a.y, wq[0][1], P0);
        P0 = fmaf(a.z, wq[0][2], P0);
        P0 = fmaf(a.w, wq[0][3], P0);
        P1 = a.x * wq[1][0];
        P1 = fmaf(a.y, wq[1][1], P1);
        P1 = fmaf(a.z, wq[1][2], P1);
        P1 = fmaf(a.w, wq[1][3], P1);
        P2 = a.x * wq[2][0];
        P2 = fmaf(a.y, wq[2][1], P2);
        P2 = fmaf(a.z, wq[2][2], P2);
        P2 = fmaf(a.w, wq[2][3], P2);
        P3 = a.x * wq[3][0];
        P3 = fmaf(a.y, wq[3][1], P3);
        P3 = fmaf(a.z, wq[3][2], P3);
        P3 = fmaf(a.w, wq[3][3], P3);
        const float n0 = P0 + fdpp<DPP_XOR1>(P1);
        const float n2 = P2 + fdpp<DPP_XOR1>(P3);
        const float t  = n0 + fdpp<DPP_XOR2>(n2);   // full dot, col = lane&31
        const float m = fmaxf(t, 0.f);              // scale folded out
        acc0 += m;
        acc1 = fmaf(ev.x, m, acc1);
        acc2 = fmaf(ev.y, m, acc2);
        acc3 = fmaf(ev.z, m, acc3);
    }
    R4[wv*64 + lane] = make_float4(acc0, acc1, acc2, acc3);
    // Se: butterfly within wave, cross-wave via LDS
    #pragma unroll
    for (int off = 1; off < 64; off <<= 1) {
        se0 += __shfl_xor(se0, off);
        se1 += __shfl_xor(se1, off);
        se2 += __shfl_xor(se2, off);
    }
    if (lane == 0) { sred[wv*3+0] = se0; sred[wv*3+1] = se1; sred[wv*3+2] = se2; }
    __syncthreads();
    // ---- combine 4 waves, apply relu scale, store accg ----
    {
        const int col = tid & 63, wq2 = tid >> 6;   // 256 threads = 64 cols x 4 w
        const float* Rf = (const float*)R4;
        float v = Rf[(0*64+col)*4 + wq2] + Rf[(1*64+col)*4 + wq2]
                + Rf[(2*64+col)*4 + wq2] + Rf[(3*64+col)*4 + wq2];
        v *= 0.35355339059327373f;                 // 0.25 * sqrt(2)
        float* accg = ws + 2048*4 + (size_t)blk*256;
        accg[((col >> 5)*4 + wq2)*32 + (col & 31)] = v;
    }
    if (tid == 0) {
        float* seg = ws + 2048 + blk*3;
        seg[0] = sred[0]+sred[3]+sred[6]+sred[9];
        seg[1] = sred[1]+sred[4]+sred[7]+sred[10];
        seg[2] = sred[2]+sred[5]+sred[8]+sred[11];
    }
}

// K3: per-node W2 + Wigner/gate algebra (unchanged, verified). 8 blocks.
__global__ __launch_bounds__(256) void k_final(
    const float* __restrict__ ws,
    const float* __restrict__ w2a,   // fc1_w2 (32x14)
    const float* __restrict__ w2b,   // fc2_w2 (32x12)
    float* __restrict__ nf_out)
{
    const int bj = blockIdx.x*256 + threadIdx.x;   // 2048
    const float inv = 1.0f / ws[bj];
    const float s  = 512.0f * inv;                 // nf0 scalar = N/norm
    const float vv0 = ws[2048 + bj*3 + 0] * inv;
    const float vv1 = ws[2048 + bj*3 + 1] * inv;
    const float vv2 = ws[2048 + bj*3 + 2] * inv;
    const float* acc = ws + 2048*4 + (size_t)bj*256;
    const float ksc = 0.17677669529663687f;        // 1/sqrt(32) (fc second layer)
    float S0[14], S1[3][14];
    #pragma unroll
    for (int cc = 0; cc < 14; cc++) { S0[cc]=0.f; S1[0][cc]=0.f; S1[1][cc]=0.f; S1[2][cc]=0.f; }
    for (int c = 0; c < 32; c++) {
        const float p = acc[c], q0 = acc[32+c], q1 = acc[64+c], q2 = acc[96+c];
        #pragma unroll
        for (int cc = 0; cc < 14; cc++) {
            const float w = w2a[c*14+cc];
            S0[cc]    = fmaf(p,  w, S0[cc]);
            S1[0][cc] = fmaf(q0, w, S1[0][cc]);
            S1[1][cc] = fmaf(q1, w, S1[1][cc]);
            S1[2][cc] = fmaf(q2, w, S1[2][cc]);
        }
    }
    #pragma unroll
    for (int cc = 0; cc < 14; cc++) { S0[cc]*=ksc; S1[0][cc]*=ksc; S1[1][cc]*=ksc; S1[2][cc]*=ksc; }
    const float is2 = 0.7071067811865476f;   // 1/sqrt2
    const float is3 = 0.5773502691896258f;   // 1/sqrt3
    float x0[4];
    #pragma unroll
    for (int k = 0; k < 4; k++)
        x0[k] = inv*is2*( s*S0[k] + is3*(vv0*S1[0][4+k] + vv1*S1[1][4+k] + vv2*S1[2][4+k]) );
    const float vv[3] = {vv0, vv1, vv2};
    float x8[3];
    #pragma unroll
    for (int k = 0; k < 3; k++)
        x8[k] = inv*is2*( s*S1[k][8] + vv[k]*S0[10] );
    const float E12_0=S1[0][12], E12_1=S1[1][12], E12_2=S1[2][12];
    float x14[3];
    x14[0] = inv*is2*(vv1*E12_2 - vv2*E12_1);
    x14[1] = inv*is2*(vv2*E12_0 - vv0*E12_2);
    x14[2] = inv*is2*(vv0*E12_1 - vv1*E12_0);
    const float a0 = fmaxf(x0[0],0.f), a1 = fmaxf(x0[1],0.f);
    const float g1 = fmaxf(x0[2],0.f), g3 = fmaxf(x0[3],0.f);
    const float p0=x8[0]*g1,  p1=x8[1]*g1,  p2=x8[2]*g1;
    const float q0_=x14[0]*g3, q1_=x14[1]*g3, q2_=x14[2]*g3;
    float T0[12], T1[3][12];
    #pragma unroll
    for (int cc = 0; cc < 12; cc++){ T0[cc]=0.f; T1[0][cc]=0.f; T1[1][cc]=0.f; T1[2][cc]=0.f; }
    const float* acc2 = acc + 128;
    for (int c = 0; c < 32; c++) {
        const float p = acc2[c], r0 = acc2[32+c], r1 = acc2[64+c], r2 = acc2[96+c];
        #pragma unroll
        for (int cc = 0; cc < 12; cc++) {
            const float w = w2b[c*12+cc];
            T0[cc]    = fmaf(p,  w, T0[cc]);
            T1[0][cc] = fmaf(r0, w, T1[0][cc]);
            T1[1][cc] = fmaf(r1, w, T1[1][cc]);
            T1[2][cc] = fmaf(r2, w, T1[2][cc]);
        }
    }
    #pragma unroll
    for (int cc = 0; cc < 12; cc++){ T0[cc]*=ksc; T1[0][cc]*=ksc; T1[1][cc]*=ksc; T1[2][cc]*=ksc; }
    const float is6  = 0.4082482904638631f;    // 1/sqrt6
    const float is12 = 0.28867513459481287f;   // 1/sqrt12
    const float E0[3] = {T1[0][0], T1[1][0], T1[2][0]};
    const float E1[3] = {T1[0][1], T1[1][1], T1[2][1]};
    const float E4[3] = {T1[0][4], T1[1][4], T1[2][4]};
    const float E8[3] = {T1[0][8], T1[1][8], T1[2][8]};
    const float cq0 = q1_*E4[2] - q2_*E4[1];
    const float cq1 = q2_*E4[0] - q0_*E4[2];
    const float cq2 = q0_*E4[1] - q1_*E4[0];
    const float cp0 = p1*E8[2] - p2*E8[1];
    const float cp1 = p2*E8[0] - p0*E8[2];
    const float cp2 = p0*E8[1] - p1*E8[0];
    float o[6];
    o[0] = inv*( is6*(a0*E0[0] + a1*E1[0]) + is6*p0*T0[2] + is12*cq0 );
    o[1] = inv*( is6*(a0*E0[1] + a1*E1[1]) + is6*p1*T0[2] + is12*cq1 );
    o[2] = inv*( is6*(a0*E0[2] + a1*E1[2]) + is6*p2*T0[2] + is12*cq2 );
    o[3] = inv*( is12*cp0 + is6*q0_*T0[10] );
    o[4] = inv*( is12*cp1 + is6*q1_*T0[10] );
    o[5] = inv*( is12*cp2 + is6*q2_*T0[10] );
    #pragma unroll
    for (int k = 0; k < 6; k++) nf_out[bj*6+k] = o[k];
}

extern "C" void kernel_launch(void* const* d_in, const int* in_sizes, int n_in,
                              void* d_out, int out_size, void* d_ws, size_t ws_size,
                              hipStream_t stream) {
    const float* disp   = (const float*)d_in[0];   // (4,16,512,512)
    const float* mask   = (const float*)d_in[1];   // (64,512,512)
    const float* coords = (const float*)d_in[2];   // (4,512,3)
    const float* fc1w1  = (const float*)d_in[3];   // (16,32)
    const float* fc1w2  = (const float*)d_in[4];   // (32,14)
    const float* fc2w1  = (const float*)d_in[5];   // (16,32)
    const float* fc2w2  = (const float*)d_in[6];   // (32,12)
    float* out = (float*)d_out;
    float* ad_out     = out;                        // 16,777,216
    float* mask_out   = out + 16777216;             // 16,777,216
    float* coords_out = out + 33554432;             // 6,144
    float* nf_out     = coords_out + 6144;          // 12,288
    float* ef_out     = nf_out + 12288;             // 4,194,304
    float* ws = (float*)d_ws;   // norm[2048] | Se[2048*3] | acc[2048*256]  (~2.03 MiB)

    k_stage  <<<2048, 256, 0, stream>>>(disp, mask, coords, ad_out, mask_out,
                                        coords_out, ef_out, ws);
    k_reduceA<<<2048, 256, 0, stream>>>(ad_out, coords, fc1w1, fc2w1, ws);
    k_final  <<<8,    256, 0, stream>>>(ws, fc1w2, fc2w2, nf_out);
}